// Round 6
// baseline (330.890 us; speedup 1.0000x reference)
//
#include <hip/hip_runtime.h>
#include <hip/hip_bf16.h>
#include <stdint.h>

#define ALPHA 1.0f

typedef __attribute__((ext_vector_type(8))) short bf16x8;
typedef __attribute__((ext_vector_type(4))) float f32x4;
typedef unsigned short ushort_t;

__device__ __forceinline__ unsigned short f32_to_bf16_rne(float f) {
    union { float f; unsigned int u; } v; v.f = f;
    unsigned int u = v.u;
    unsigned int r = u + 0x7FFFu + ((u >> 16) & 1u);
    return (unsigned short)(r >> 16);
}

// packed f32x2 -> bf16x2 (RNE), single VALU instruction; word = [lo | hi<<16]
__device__ __forceinline__ unsigned int cvt_pk_bf16(float lo, float hi) {
    unsigned int r;
    asm("v_cvt_pk_bf16_f32 %0, %1, %2" : "=v"(r) : "v"(lo), "v"(hi));
    return r;
}

__device__ __forceinline__ void async_copy16(const void* g, void* l) {
    __builtin_amdgcn_global_load_lds(
        (const __attribute__((address_space(1))) void*)g,
        (__attribute__((address_space(3))) void*)l, 16, 0, 0);
}

// ---------------------------------------------------------------------------
// Fused W_eff: weff[o][i] = W[o][i] + ALPHA * sum_r fac[o][r] * t1[r][i]
//   fac = up_aux @ lora_up  (1024 x 4, computed redundantly per block: 200 FMA)
//   t1  = lora_down @ down_aux (4 x 1024, each thread computes its 4 columns)
// Replaces the serial t2 kernel + weff kernel with ONE parallel kernel.
template <bool BF16OUT>
__global__ __launch_bounds__(256)
void weff_fused_kernel(const float* __restrict__ W,
                       const float* __restrict__ lora_down,
                       const float* __restrict__ lora_up,
                       const float* __restrict__ down_aux,
                       const float* __restrict__ up_aux,
                       void* __restrict__ weff) {
    int o = blockIdx.x;
    int i0 = threadIdx.x * 4;

    float fac[4] = {0.f, 0.f, 0.f, 0.f};
    for (int u = 0; u < 50; ++u) {
        float ua = up_aux[o * 50 + u] * ALPHA;
#pragma unroll
        for (int r = 0; r < 4; ++r) fac[r] += ua * lora_up[u * 4 + r];
    }

    float4 t1[4];
#pragma unroll
    for (int r = 0; r < 4; ++r) t1[r] = make_float4(0.f, 0.f, 0.f, 0.f);
    for (int d = 0; d < 100; ++d) {
        float4 da = *(const float4*)(down_aux + d * 1024 + i0);
#pragma unroll
        for (int r = 0; r < 4; ++r) {
            float ld = lora_down[r * 100 + d];
            t1[r].x += ld * da.x; t1[r].y += ld * da.y;
            t1[r].z += ld * da.z; t1[r].w += ld * da.w;
        }
    }

    float4 acc = *(const float4*)(W + (long)o * 1024 + i0);
#pragma unroll
    for (int r = 0; r < 4; ++r) {
        acc.x += fac[r] * t1[r].x; acc.y += fac[r] * t1[r].y;
        acc.z += fac[r] * t1[r].z; acc.w += fac[r] * t1[r].w;
    }

    if (BF16OUT) {
        ushort4 rr;
        rr.x = f32_to_bf16_rne(acc.x); rr.y = f32_to_bf16_rne(acc.y);
        rr.z = f32_to_bf16_rne(acc.z); rr.w = f32_to_bf16_rne(acc.w);
        *(ushort4*)((ushort_t*)weff + (long)o * 1024 + i0) = rr;
    } else {
        *(float4*)((float*)weff + (long)o * 1024 + i0) = acc;
    }
}

// ---------------------------------------------------------------------------
// hidden_states f32 -> bf16, 8 elems/thread/iter (16B stores)
__global__ __launch_bounds__(256)
void cvt_bf16_kernel(const float* __restrict__ in, ushort_t* __restrict__ out, long n8) {
    long idx = (long)blockIdx.x * blockDim.x + threadIdx.x;
    long stride = (long)gridDim.x * blockDim.x;
    for (long i = idx; i < n8; i += stride) {
        const float4* p = (const float4*)(in + i * 8);
        float4 a = p[0], b = p[1];
        uint4 w;
        w.x = cvt_pk_bf16(a.x, a.y);
        w.y = cvt_pk_bf16(a.z, a.w);
        w.z = cvt_pk_bf16(b.x, b.y);
        w.w = cvt_pk_bf16(b.z, b.w);
        ((uint4*)out)[i] = w;
    }
}

// ---------------------------------------------------------------------------
// 256x256x64 8-phase bf16 GEMM:  C = A(bf16 MxK) * Bt(bf16 NxK)^T + bias
//
// 8 waves (2M x 4N), per-wave 128x64 output = acc[8][4] f32x4.
// LDS: 2-tile double buffer, A/B each [256][64] bf16 (32 KB) = 128 KB total.
// Both tiles 16B-chunk XOR-swizzled (chunk' = chunk ^ (row&7)); staged via
// global_load_lds with PRE-SWIZZLED global source (rule #21, R4/R5-verified
// zero-conflict for both the glds write and the b128 fragment reads).
//
// Per K-tile: 4 phases, each {issue 1 half-tile stage (2 glds) | ds_read
// subtile | s_barrier | setprio(1) 16 MFMA setprio(0) | s_barrier}.
// Quadrants: P0: aL,bL read -> m0-3 x n0-1 ; P1: bH read -> m0-3 x n2-3 ;
//            P2: aH read -> m4-7 x n2-3 ; P3: (regs live) -> m4-7 x n0-1.
// Stage placement (counted-vmcnt pipeline, NEVER vmcnt(0) in steady state):
//   iter j: P0/P1 stage A-halves of tile j+1 -> buf j+1 (A slots freed at
//   j-1.P2); P2/P3 stage B-halves of tile j+2 -> buf j (B slots freed at
//   j.P1). At j.P3 end: vmcnt(4) retires exactly tile j+1's 8 loads,
//   leaving tile j+2's 4 B-loads in flight. Raw s_barrier everywhere (no
//   implicit vmcnt(0) drain).
#define BMM 256
#define BNN 256
#define BKK 64

__global__ __launch_bounds__(512, 2)
void gemm_8ph_kernel(const ushort_t* __restrict__ A,
                     const ushort_t* __restrict__ Bt,
                     const float* __restrict__ bias,
                     float* __restrict__ C, int M, int N, int K) {
    __shared__ __align__(16) ushort_t Ab[2][BMM * BKK];  // 2 x 32 KB
    __shared__ __align__(16) ushort_t Bb[2][BNN * BKK];  // 2 x 32 KB

    int nTilesN = N / BNN;  // 4
    int nwg = gridDim.x;
    int bid = blockIdx.x;
    int swz = bid;
    if ((nwg & 7) == 0) {   // grid = 1024 -> bijective XCD swizzle
        int cpx = nwg >> 3;
        swz = (bid & 7) * cpx + (bid >> 3);
    }
    int tm = swz / nTilesN;
    int tn = swz % nTilesN;
    const long rowA0 = (long)tm * BMM;
    const long colB0 = (long)tn * BNN;

    int tid = threadIdx.x;
    int lane = tid & 63;
    int wave = tid >> 6;     // 0..7
    int wr = wave >> 2;      // 0..1  (M)
    int wc = wave & 3;       // 0..3  (N)

    // staging map: chunk pc = q*512 + tid covers 16B; row-in-half = pc>>3,
    // stored chunk = pc&7, logical (global) chunk = (pc&7) ^ (row&7)
    int prow[2], pcg[2];
#pragma unroll
    for (int q = 0; q < 2; ++q) {
        int pc = q * 512 + tid;
        prow[q] = pc >> 3;
        pcg[q] = (pc & 7) ^ (prow[q] & 7);
    }

    // fragment map
    int fr = lane & 15;
    int h4 = lane >> 4;
    int s7 = fr & 7;
    int aoff = (wr * 128 + fr) * 64;
    int boff = (wc * 64 + fr) * 64;
    int ck[2] = { (h4 ^ s7) * 8, ((4 + h4) ^ s7) * 8 };  // elem offs, kk=0/1

    f32x4 acc[8][4];
#pragma unroll
    for (int m = 0; m < 8; ++m)
#pragma unroll
        for (int n = 0; n < 4; ++n) acc[m][n] = (f32x4)(0.0f);

    const int nIter = K / BKK;  // 16

    auto stageA = [&](int kt, int h, int bufsel) {
        const ushort_t* src = A + (rowA0 + h * 128) * (long)K + kt * BKK;
        ushort_t* dst = &Ab[bufsel][h * 8192 + wave * 512];
#pragma unroll
        for (int q = 0; q < 2; ++q)
            async_copy16(src + (long)prow[q] * K + pcg[q] * 8, dst + q * 4096);
    };
    auto stageB = [&](int kt, int h, int bufsel) {
        const ushort_t* src = Bt + (colB0 + h * 128) * (long)K + kt * BKK;
        ushort_t* dst = &Bb[bufsel][h * 8192 + wave * 512];
#pragma unroll
        for (int q = 0; q < 2; ++q)
            async_copy16(src + (long)prow[q] * K + pcg[q] * 8, dst + q * 4096);
    };

    // ---------------- prologue: 12 glds ----------------
    stageB(0, 0, 0); stageB(0, 1, 0);       // oldest: tile0 B
    stageA(0, 0, 0); stageA(0, 1, 0);       // tile0 A
    stageB(1, 0, 1); stageB(1, 1, 1);       // tile1 B (stays in flight)
    asm volatile("s_waitcnt vmcnt(4)" ::: "memory");  // tile0 landed
    __builtin_amdgcn_s_barrier();

    bf16x8 aL[4][2], aH[4][2], bL[2][2], bH[2][2];

#pragma unroll 1
    for (int j = 0; j < nIter; ++j) {
        int c = j & 1, o = c ^ 1;
        const ushort_t* Ac = &Ab[c][0];
        const ushort_t* Bc = &Bb[c][0];

        // ---- Phase 0: stage A-half0(j+1); read aL, bL; MFMA m0-3 x n0-1 ----
        if (j + 1 < nIter) stageA(j + 1, 0, o);
#pragma unroll
        for (int m = 0; m < 4; ++m)
#pragma unroll
            for (int kk = 0; kk < 2; ++kk)
                aL[m][kk] = *(const bf16x8*)&Ac[aoff + m * 1024 + ck[kk]];
#pragma unroll
        for (int n = 0; n < 2; ++n)
#pragma unroll
            for (int kk = 0; kk < 2; ++kk)
                bL[n][kk] = *(const bf16x8*)&Bc[boff + n * 1024 + ck[kk]];
        __builtin_amdgcn_s_barrier();
        __builtin_amdgcn_s_setprio(1);
#pragma unroll
        for (int m = 0; m < 4; ++m)
#pragma unroll
            for (int n = 0; n < 2; ++n)
#pragma unroll
                for (int kk = 0; kk < 2; ++kk)
                    acc[m][n] = __builtin_amdgcn_mfma_f32_16x16x32_bf16(
                        aL[m][kk], bL[n][kk], acc[m][n], 0, 0, 0);
        __builtin_amdgcn_s_setprio(0);
        __builtin_amdgcn_s_barrier();

        // ---- Phase 1: stage A-half1(j+1); read bH; MFMA m0-3 x n2-3 ----
        if (j + 1 < nIter) stageA(j + 1, 1, o);
#pragma unroll
        for (int n = 0; n < 2; ++n)
#pragma unroll
            for (int kk = 0; kk < 2; ++kk)
                bH[n][kk] = *(const bf16x8*)&Bc[boff + (n + 2) * 1024 + ck[kk]];
        __builtin_amdgcn_s_barrier();
        __builtin_amdgcn_s_setprio(1);
#pragma unroll
        for (int m = 0; m < 4; ++m)
#pragma unroll
            for (int n = 0; n < 2; ++n)
#pragma unroll
                for (int kk = 0; kk < 2; ++kk)
                    acc[m][n + 2] = __builtin_amdgcn_mfma_f32_16x16x32_bf16(
                        aL[m][kk], bH[n][kk], acc[m][n + 2], 0, 0, 0);
        __builtin_amdgcn_s_setprio(0);
        __builtin_amdgcn_s_barrier();

        // ---- Phase 2: stage B-half0(j+2); read aH; MFMA m4-7 x n2-3 ----
        if (j + 2 < nIter) stageB(j + 2, 0, c);
#pragma unroll
        for (int m = 0; m < 4; ++m)
#pragma unroll
            for (int kk = 0; kk < 2; ++kk)
                aH[m][kk] = *(const bf16x8*)&Ac[aoff + (m + 4) * 1024 + ck[kk]];
        __builtin_amdgcn_s_barrier();
        __builtin_amdgcn_s_setprio(1);
#pragma unroll
        for (int m = 0; m < 4; ++m)
#pragma unroll
            for (int n = 0; n < 2; ++n)
#pragma unroll
                for (int kk = 0; kk < 2; ++kk)
                    acc[m + 4][n + 2] = __builtin_amdgcn_mfma_f32_16x16x32_bf16(
                        aH[m][kk], bH[n][kk], acc[m + 4][n + 2], 0, 0, 0);
        __builtin_amdgcn_s_setprio(0);
        __builtin_amdgcn_s_barrier();

        // ---- Phase 3: stage B-half1(j+2); MFMA m4-7 x n0-1; vmcnt gate ----
        if (j + 2 < nIter) stageB(j + 2, 1, c);
        __builtin_amdgcn_s_barrier();
        __builtin_amdgcn_s_setprio(1);
#pragma unroll
        for (int m = 0; m < 4; ++m)
#pragma unroll
            for (int n = 0; n < 2; ++n)
#pragma unroll
                for (int kk = 0; kk < 2; ++kk)
                    acc[m + 4][n] = __builtin_amdgcn_mfma_f32_16x16x32_bf16(
                        aH[m][kk], bL[n][kk], acc[m + 4][n], 0, 0, 0);
        __builtin_amdgcn_s_setprio(0);
        if (j + 2 < nIter) {
            asm volatile("s_waitcnt vmcnt(4)" ::: "memory");  // tile j+1 landed
        } else if (j + 2 == nIter) {
            asm volatile("s_waitcnt vmcnt(0)" ::: "memory");  // last A stage
        }
        __builtin_amdgcn_s_barrier();
    }

    // ---- epilogue: C = acc + bias ----
    int ccol = lane & 15;
    int crow = (lane >> 4) * 4;
#pragma unroll
    for (int m = 0; m < 8; ++m) {
        long grow = rowA0 + wr * 128 + m * 16 + crow;
#pragma unroll
        for (int n = 0; n < 4; ++n) {
            long gcol = colB0 + wc * 64 + n * 16 + ccol;
            float bb = bias[gcol];
#pragma unroll
            for (int r = 0; r < 4; ++r) {
                C[(grow + r) * N + gcol] = acc[m][n][r] + bb;
            }
        }
    }
}

// ---------------------------------------------------------------------------
// Fallback: plain f32 tiled GEMM (used only if ws too small for bf16 path)
__global__ __launch_bounds__(256)
void gemm_f32_fallback(const float* __restrict__ A, const float* __restrict__ Bt,
                       const float* __restrict__ bias, float* __restrict__ C,
                       int M, int N, int K) {
    __shared__ float As[64][17];
    __shared__ float Bs[64][17];
    int tilesN = N / 64;
    int tm = blockIdx.x / tilesN;
    int tn = blockIdx.x % tilesN;
    int tid = threadIdx.x;
    int tr = tid / 16, tc = tid % 16;
    float acc[4][4] = {};
    for (int k0 = 0; k0 < K; k0 += 16) {
        for (int t = tid; t < 64 * 16; t += 256) {
            int r = t / 16, c = t % 16;
            As[r][c] = A[((long)tm * 64 + r) * K + k0 + c];
            Bs[r][c] = Bt[((long)tn * 64 + r) * K + k0 + c];
        }
        __syncthreads();
#pragma unroll
        for (int kk = 0; kk < 16; ++kk) {
            float av[4], bv[4];
#pragma unroll
            for (int i = 0; i < 4; ++i) av[i] = As[tr * 4 + i][kk];
#pragma unroll
            for (int j = 0; j < 4; ++j) bv[j] = Bs[tc * 4 + j][kk];
#pragma unroll
            for (int i = 0; i < 4; ++i)
#pragma unroll
                for (int j = 0; j < 4; ++j) acc[i][j] += av[i] * bv[j];
        }
        __syncthreads();
    }
#pragma unroll
    for (int i = 0; i < 4; ++i) {
        long row = (long)tm * 64 + tr * 4 + i;
#pragma unroll
        for (int j = 0; j < 4; ++j) {
            long col = (long)tn * 64 + tc * 4 + j;
            C[row * N + col] = acc[i][j] + bias[col];
        }
    }
}

// ---------------------------------------------------------------------------
extern "C" void kernel_launch(void* const* d_in, const int* in_sizes, int n_in,
                              void* d_out, int out_size, void* d_ws, size_t ws_size,
                              hipStream_t stream) {
    const float* hs        = (const float*)d_in[0];
    const float* W         = (const float*)d_in[1];
    const float* b         = (const float*)d_in[2];
    const float* lora_down = (const float*)d_in[3];
    const float* lora_up   = (const float*)d_in[4];
    const float* down_aux  = (const float*)d_in[5];
    const float* up_aux    = (const float*)d_in[6];
    float* out = (float*)d_out;

    const int K = 1024;   // IN
    const int N = 1024;   // OUT
    const int M = in_sizes[0] / K;  // B*S = 65536

    char* ws = (char*)d_ws;
    // fast path layout: weff bf16 @0 (2MB), hsbf @4MB (M*K*2 = 128MB)
    const size_t OFF_HSBF = 4 * 1024 * 1024;
    const size_t NEED_FAST = OFF_HSBF + (size_t)M * K * sizeof(ushort_t);

    if (ws_size >= NEED_FAST && (M % BMM) == 0) {
        ushort_t* weff = (ushort_t*)ws;
        ushort_t* hsbf = (ushort_t*)(ws + OFF_HSBF);
        weff_fused_kernel<true><<<N, 256, 0, stream>>>(W, lora_down, lora_up,
                                                       down_aux, up_aux, weff);
        long n8 = (long)M * K / 8;
        cvt_bf16_kernel<<<2048, 256, 0, stream>>>(hs, hsbf, n8);
        int grid = (M / BMM) * (N / BNN);   // 1024
        gemm_8ph_kernel<<<grid, 512, 0, stream>>>(hsbf, weff, b, out, M, N, K);
    } else {
        float* weff = (float*)ws;  // 4MB
        weff_fused_kernel<false><<<N, 256, 0, stream>>>(W, lora_down, lora_up,
                                                        down_aux, up_aux, weff);
        int grid = (M / 64) * (N / 64);
        gemm_f32_fallback<<<grid, 256, 0, stream>>>(hs, weff, b, out, M, N, K);
    }
}

// Round 7
// 297.328 us; speedup vs baseline: 1.1129x; 1.1129x over previous
//
#include <hip/hip_runtime.h>
#include <hip/hip_bf16.h>
#include <stdint.h>

#define ALPHA 1.0f

typedef __attribute__((ext_vector_type(8))) short bf16x8;
typedef __attribute__((ext_vector_type(4))) float f32x4;
typedef unsigned short ushort_t;

__device__ __forceinline__ unsigned short f32_to_bf16_rne(float f) {
    union { float f; unsigned int u; } v; v.f = f;
    unsigned int u = v.u;
    unsigned int r = u + 0x7FFFu + ((u >> 16) & 1u);
    return (unsigned short)(r >> 16);
}

__device__ __forceinline__ unsigned int cvt_pk_bf16(float lo, float hi) {
    unsigned int r;
    asm("v_cvt_pk_bf16_f32 %0, %1, %2" : "=v"(r) : "v"(lo), "v"(hi));
    return r;
}

__device__ __forceinline__ void async_copy16(const void* g, void* l) {
    __builtin_amdgcn_global_load_lds(
        (const __attribute__((address_space(1))) void*)g,
        (__attribute__((address_space(3))) void*)l, 16, 0, 0);
}

// ---------------------------------------------------------------------------
// Fused W_eff: weff[o][i] = W[o][i] + ALPHA * sum_r fac[o][r] * t1[r][i]
template <bool BF16OUT>
__global__ __launch_bounds__(256)
void weff_fused_kernel(const float* __restrict__ W,
                       const float* __restrict__ lora_down,
                       const float* __restrict__ lora_up,
                       const float* __restrict__ down_aux,
                       const float* __restrict__ up_aux,
                       void* __restrict__ weff) {
    int o = blockIdx.x;
    int i0 = threadIdx.x * 4;

    float fac[4] = {0.f, 0.f, 0.f, 0.f};
    for (int u = 0; u < 50; ++u) {
        float ua = up_aux[o * 50 + u] * ALPHA;
#pragma unroll
        for (int r = 0; r < 4; ++r) fac[r] += ua * lora_up[u * 4 + r];
    }

    float4 t1[4];
#pragma unroll
    for (int r = 0; r < 4; ++r) t1[r] = make_float4(0.f, 0.f, 0.f, 0.f);
    for (int d = 0; d < 100; ++d) {
        float4 da = *(const float4*)(down_aux + d * 1024 + i0);
#pragma unroll
        for (int r = 0; r < 4; ++r) {
            float ld = lora_down[r * 100 + d];
            t1[r].x += ld * da.x; t1[r].y += ld * da.y;
            t1[r].z += ld * da.z; t1[r].w += ld * da.w;
        }
    }

    float4 acc = *(const float4*)(W + (long)o * 1024 + i0);
#pragma unroll
    for (int r = 0; r < 4; ++r) {
        acc.x += fac[r] * t1[r].x; acc.y += fac[r] * t1[r].y;
        acc.z += fac[r] * t1[r].z; acc.w += fac[r] * t1[r].w;
    }

    if (BF16OUT) {
        ushort4 rr;
        rr.x = f32_to_bf16_rne(acc.x); rr.y = f32_to_bf16_rne(acc.y);
        rr.z = f32_to_bf16_rne(acc.z); rr.w = f32_to_bf16_rne(acc.w);
        *(ushort4*)((ushort_t*)weff + (long)o * 1024 + i0) = rr;
    } else {
        *(float4*)((float*)weff + (long)o * 1024 + i0) = acc;
    }
}

// ---------------------------------------------------------------------------
// hidden_states f32 -> bf16, 8 elems/thread/iter (16B stores)
__global__ __launch_bounds__(256)
void cvt_bf16_kernel(const float* __restrict__ in, ushort_t* __restrict__ out, long n8) {
    long idx = (long)blockIdx.x * blockDim.x + threadIdx.x;
    long stride = (long)gridDim.x * blockDim.x;
    for (long i = idx; i < n8; i += stride) {
        const float4* p = (const float4*)(in + i * 8);
        float4 a = p[0], b = p[1];
        uint4 w;
        w.x = cvt_pk_bf16(a.x, a.y);
        w.y = cvt_pk_bf16(a.z, a.w);
        w.z = cvt_pk_bf16(b.x, b.y);
        w.w = cvt_pk_bf16(b.z, b.w);
        ((uint4*)out)[i] = w;
    }
}

// ---------------------------------------------------------------------------
// 256x256x64 bf16 GEMM, 2-barrier/K-tile counted-sync schedule.
//   C = A(bf16 MxK) * Bt(bf16 NxK)^T + bias
//
// 8 waves (2M x 4N), per-wave 128x64 output = acc[8][4] f32x4 (AGPR).
// LDS: 2-tile double buffer, A/B each [256][64] bf16 = 128 KB total.
// 16B-chunk XOR swizzle (chunk' = chunk ^ (row&7)), staged via glds with
// pre-swizzled global source (R6-verified: 0 bank conflicts).
//
// Per K-tile j (buf c = j&1):
//   [B0 from prev iter]  (all tile-j glds published)
//   issue ALL 24 ds_read_b128 (aL, bL, bH, aH)  -- compiler emits COUNTED
//     lgkm waits: Q0 waits first 12, Q1 first 16, Q2 all -> bH/aH LDS
//     transfer streams UNDER Q0/Q1 MFMA.
//   Q0 (aLxbL), Q1 (aLxbH), Q2 (aHxbH)      [48 MFMA]
//   s_barrier (B2)   -- every wave passed lgkm(0) before Q2's tail, so all
//     reads of buf c are chip-wide complete -> safe to overwrite
//   stage tile j+2 -> buf c (8 glds, fire-and-forget)
//   Q3 (aHxbL, pure-reg)                     [16 MFMA, overlaps glds flight]
//   s_waitcnt vmcnt(8)  -- tile j+1 landed; tile j+2's 8 stay in flight
//   s_barrier (B0)
#define BMM 256
#define BNN 256
#define BKK 64

__global__ __launch_bounds__(512, 2)
void gemm_2bar_kernel(const ushort_t* __restrict__ A,
                      const ushort_t* __restrict__ Bt,
                      const float* __restrict__ bias,
                      float* __restrict__ C, int M, int N, int K) {
    __shared__ __align__(16) ushort_t Ab[2][BMM * BKK];  // 2 x 32 KB
    __shared__ __align__(16) ushort_t Bb[2][BNN * BKK];  // 2 x 32 KB

    int nTilesN = N / BNN;  // 4
    int nwg = gridDim.x;
    int bid = blockIdx.x;
    int swz = bid;
    if ((nwg & 7) == 0) {   // grid = 1024 -> bijective XCD swizzle
        int cpx = nwg >> 3;
        swz = (bid & 7) * cpx + (bid >> 3);
    }
    int tm = swz / nTilesN;
    int tn = swz % nTilesN;
    const long rowA0 = (long)tm * BMM;
    const long colB0 = (long)tn * BNN;

    int tid = threadIdx.x;
    int lane = tid & 63;
    int wave = tid >> 6;     // 0..7
    int wr = wave >> 2;      // 0..1  (M)
    int wc = wave & 3;       // 0..3  (N)

    // staging map: chunk pc = q*512 + tid covers 16B; row-in-half = pc>>3,
    // stored chunk = pc&7, logical (global) chunk = (pc&7) ^ (row&7)
    int prow[2], pcg[2];
#pragma unroll
    for (int q = 0; q < 2; ++q) {
        int pc = q * 512 + tid;
        prow[q] = pc >> 3;
        pcg[q] = (pc & 7) ^ (prow[q] & 7);
    }

    // fragment map
    int fr = lane & 15;
    int h4 = lane >> 4;
    int s7 = fr & 7;
    int aoff = (wr * 128 + fr) * 64;
    int boff = (wc * 64 + fr) * 64;
    int ck[2] = { (h4 ^ s7) * 8, ((4 + h4) ^ s7) * 8 };  // elem offs, kk=0/1

    f32x4 acc[8][4];
#pragma unroll
    for (int m = 0; m < 8; ++m)
#pragma unroll
        for (int n = 0; n < 4; ++n) acc[m][n] = (f32x4)(0.0f);

    const int nIter = K / BKK;  // 16

    auto stageA = [&](int kt, int h, int bufsel) {
        const ushort_t* src = A + (rowA0 + h * 128) * (long)K + kt * BKK;
        ushort_t* dst = &Ab[bufsel][h * 8192 + wave * 512];
#pragma unroll
        for (int q = 0; q < 2; ++q)
            async_copy16(src + (long)prow[q] * K + pcg[q] * 8, dst + q * 4096);
    };
    auto stageB = [&](int kt, int h, int bufsel) {
        const ushort_t* src = Bt + (colB0 + h * 128) * (long)K + kt * BKK;
        ushort_t* dst = &Bb[bufsel][h * 8192 + wave * 512];
#pragma unroll
        for (int q = 0; q < 2; ++q)
            async_copy16(src + (long)prow[q] * K + pcg[q] * 8, dst + q * 4096);
    };

    // ---------------- prologue: tile0 -> buf0, tile1 -> buf1 ----------------
    stageA(0, 0, 0); stageA(0, 1, 0); stageB(0, 0, 0); stageB(0, 1, 0);
    stageA(1, 0, 1); stageA(1, 1, 1); stageB(1, 0, 1); stageB(1, 1, 1);
    asm volatile("s_waitcnt vmcnt(8)" ::: "memory");  // tile0 landed
    __builtin_amdgcn_s_barrier();

#pragma unroll 1
    for (int j = 0; j < nIter; ++j) {
        int c = j & 1;
        const ushort_t* Ac = &Ab[c][0];
        const ushort_t* Bc = &Bb[c][0];

        // ---- issue ALL fragment reads for tile j (order: aL, bL, bH, aH) --
        bf16x8 aL[4][2], aH[4][2], bL[2][2], bH[2][2];
#pragma unroll
        for (int m = 0; m < 4; ++m)
#pragma unroll
            for (int kk = 0; kk < 2; ++kk)
                aL[m][kk] = *(const bf16x8*)&Ac[aoff + m * 1024 + ck[kk]];
#pragma unroll
        for (int n = 0; n < 2; ++n)
#pragma unroll
            for (int kk = 0; kk < 2; ++kk)
                bL[n][kk] = *(const bf16x8*)&Bc[boff + n * 1024 + ck[kk]];
#pragma unroll
        for (int n = 0; n < 2; ++n)
#pragma unroll
            for (int kk = 0; kk < 2; ++kk)
                bH[n][kk] = *(const bf16x8*)&Bc[boff + (n + 2) * 1024 + ck[kk]];
#pragma unroll
        for (int m = 0; m < 4; ++m)
#pragma unroll
            for (int kk = 0; kk < 2; ++kk)
                aH[m][kk] = *(const bf16x8*)&Ac[aoff + (m + 4) * 1024 + ck[kk]];

        // ---- Q0, Q1, Q2 (compiler inserts counted lgkm before each) ----
        __builtin_amdgcn_s_setprio(1);
#pragma unroll
        for (int m = 0; m < 4; ++m)
#pragma unroll
            for (int n = 0; n < 2; ++n)
#pragma unroll
                for (int kk = 0; kk < 2; ++kk)
                    acc[m][n] = __builtin_amdgcn_mfma_f32_16x16x32_bf16(
                        aL[m][kk], bL[n][kk], acc[m][n], 0, 0, 0);
#pragma unroll
        for (int m = 0; m < 4; ++m)
#pragma unroll
            for (int n = 0; n < 2; ++n)
#pragma unroll
                for (int kk = 0; kk < 2; ++kk)
                    acc[m][n + 2] = __builtin_amdgcn_mfma_f32_16x16x32_bf16(
                        aL[m][kk], bH[n][kk], acc[m][n + 2], 0, 0, 0);
#pragma unroll
        for (int m = 0; m < 4; ++m)
#pragma unroll
            for (int n = 0; n < 2; ++n)
#pragma unroll
                for (int kk = 0; kk < 2; ++kk)
                    acc[m + 4][n + 2] = __builtin_amdgcn_mfma_f32_16x16x32_bf16(
                        aH[m][kk], bH[n][kk], acc[m + 4][n + 2], 0, 0, 0);
        __builtin_amdgcn_s_setprio(0);

        // all waves have lgkm(0)'d (Q2 used the last reads) -> buf c reusable
        __builtin_amdgcn_s_barrier();            // B2

        if (j + 2 < nIter) {                     // stage tile j+2 -> buf c
            stageA(j + 2, 0, c); stageA(j + 2, 1, c);
            stageB(j + 2, 0, c); stageB(j + 2, 1, c);
        }

        // ---- Q3 (pure-reg; overlaps the glds flight) ----
        __builtin_amdgcn_s_setprio(1);
#pragma unroll
        for (int m = 0; m < 4; ++m)
#pragma unroll
            for (int n = 0; n < 2; ++n)
#pragma unroll
                for (int kk = 0; kk < 2; ++kk)
                    acc[m + 4][n] = __builtin_amdgcn_mfma_f32_16x16x32_bf16(
                        aH[m][kk], bL[n][kk], acc[m + 4][n], 0, 0, 0);
        __builtin_amdgcn_s_setprio(0);

        // gate: tile j+1 landed (j+2's 8 glds stay in flight)
        if (j + 2 < nIter) {
            asm volatile("s_waitcnt vmcnt(8)" ::: "memory");
        } else {
            asm volatile("s_waitcnt vmcnt(0)" ::: "memory");
        }
        __builtin_amdgcn_s_barrier();            // B0 (publish for next iter)
    }

    // ---- epilogue: C = acc + bias ----
    int ccol = lane & 15;
    int crow = (lane >> 4) * 4;
#pragma unroll
    for (int m = 0; m < 8; ++m) {
        long grow = rowA0 + wr * 128 + m * 16 + crow;
#pragma unroll
        for (int n = 0; n < 4; ++n) {
            long gcol = colB0 + wc * 64 + n * 16 + ccol;
            float bb = bias[gcol];
#pragma unroll
            for (int r = 0; r < 4; ++r) {
                C[(grow + r) * N + gcol] = acc[m][n][r] + bb;
            }
        }
    }
}

// ---------------------------------------------------------------------------
// Fallback: plain f32 tiled GEMM (used only if ws too small for bf16 path)
__global__ __launch_bounds__(256)
void gemm_f32_fallback(const float* __restrict__ A, const float* __restrict__ Bt,
                       const float* __restrict__ bias, float* __restrict__ C,
                       int M, int N, int K) {
    __shared__ float As[64][17];
    __shared__ float Bs[64][17];
    int tilesN = N / 64;
    int tm = blockIdx.x / tilesN;
    int tn = blockIdx.x % tilesN;
    int tid = threadIdx.x;
    int tr = tid / 16, tc = tid % 16;
    float acc[4][4] = {};
    for (int k0 = 0; k0 < K; k0 += 16) {
        for (int t = tid; t < 64 * 16; t += 256) {
            int r = t / 16, c = t % 16;
            As[r][c] = A[((long)tm * 64 + r) * K + k0 + c];
            Bs[r][c] = Bt[((long)tn * 64 + r) * K + k0 + c];
        }
        __syncthreads();
#pragma unroll
        for (int kk = 0; kk < 16; ++kk) {
            float av[4], bv[4];
#pragma unroll
            for (int i = 0; i < 4; ++i) av[i] = As[tr * 4 + i][kk];
#pragma unroll
            for (int j = 0; j < 4; ++j) bv[j] = Bs[tc * 4 + j][kk];
#pragma unroll
            for (int i = 0; i < 4; ++i)
#pragma unroll
                for (int j = 0; j < 4; ++j) acc[i][j] += av[i] * bv[j];
        }
        __syncthreads();
    }
#pragma unroll
    for (int i = 0; i < 4; ++i) {
        long row = (long)tm * 64 + tr * 4 + i;
#pragma unroll
        for (int j = 0; j < 4; ++j) {
            long col = (long)tn * 64 + tc * 4 + j;
            C[row * N + col] = acc[i][j] + bias[col];
        }
    }
}

// ---------------------------------------------------------------------------
extern "C" void kernel_launch(void* const* d_in, const int* in_sizes, int n_in,
                              void* d_out, int out_size, void* d_ws, size_t ws_size,
                              hipStream_t stream) {
    const float* hs        = (const float*)d_in[0];
    const float* W         = (const float*)d_in[1];
    const float* b         = (const float*)d_in[2];
    const float* lora_down = (const float*)d_in[3];
    const float* lora_up   = (const float*)d_in[4];
    const float* down_aux  = (const float*)d_in[5];
    const float* up_aux    = (const float*)d_in[6];
    float* out = (float*)d_out;

    const int K = 1024;   // IN
    const int N = 1024;   // OUT
    const int M = in_sizes[0] / K;  // B*S = 65536

    char* ws = (char*)d_ws;
    const size_t OFF_HSBF = 4 * 1024 * 1024;
    const size_t NEED_FAST = OFF_HSBF + (size_t)M * K * sizeof(ushort_t);

    if (ws_size >= NEED_FAST && (M % BMM) == 0) {
        ushort_t* weff = (ushort_t*)ws;
        ushort_t* hsbf = (ushort_t*)(ws + OFF_HSBF);
        weff_fused_kernel<true><<<N, 256, 0, stream>>>(W, lora_down, lora_up,
                                                       down_aux, up_aux, weff);
        long n8 = (long)M * K / 8;
        cvt_bf16_kernel<<<4096, 256, 0, stream>>>(hs, hsbf, n8);
        int grid = (M / BMM) * (N / BNN);   // 1024
        gemm_2bar_kernel<<<grid, 512, 0, stream>>>(hsbf, weff, b, out, M, N, K);
    } else {
        float* weff = (float*)ws;  // 4MB
        weff_fused_kernel<false><<<N, 256, 0, stream>>>(W, lora_down, lora_up,
                                                        down_aux, up_aux, weff);
        int grid = (M / 64) * (N / 64);
        gemm_f32_fallback<<<grid, 256, 0, stream>>>(hs, weff, b, out, M, N, K);
    }
}

// Round 8
// 229.254 us; speedup vs baseline: 1.4433x; 1.2969x over previous
//
#include <hip/hip_runtime.h>
#include <hip/hip_bf16.h>
#include <stdint.h>

#define ALPHA 1.0f

typedef __attribute__((ext_vector_type(8))) short bf16x8;
typedef __attribute__((ext_vector_type(4))) float f32x4;
typedef unsigned short ushort_t;

__device__ __forceinline__ unsigned short f32_to_bf16_rne(float f) {
    union { float f; unsigned int u; } v; v.f = f;
    unsigned int u = v.u;
    unsigned int r = u + 0x7FFFu + ((u >> 16) & 1u);
    return (unsigned short)(r >> 16);
}

__device__ __forceinline__ unsigned int cvt_pk_bf16(float lo, float hi) {
    unsigned int r;
    asm("v_cvt_pk_bf16_f32 %0, %1, %2" : "=v"(r) : "v"(lo), "v"(hi));
    return r;
}

__device__ __forceinline__ void async_copy16(const void* g, void* l) {
    __builtin_amdgcn_global_load_lds(
        (const __attribute__((address_space(1))) void*)g,
        (__attribute__((address_space(3))) void*)l, 16, 0, 0);
}

// ---------------------------------------------------------------------------
// Fused W_eff: weff[o][i] = W[o][i] + ALPHA * sum_r fac[o][r] * t1[r][i]
template <bool BF16OUT>
__global__ __launch_bounds__(256)
void weff_fused_kernel(const float* __restrict__ W,
                       const float* __restrict__ lora_down,
                       const float* __restrict__ lora_up,
                       const float* __restrict__ down_aux,
                       const float* __restrict__ up_aux,
                       void* __restrict__ weff) {
    int o = blockIdx.x;
    int i0 = threadIdx.x * 4;

    float fac[4] = {0.f, 0.f, 0.f, 0.f};
    for (int u = 0; u < 50; ++u) {
        float ua = up_aux[o * 50 + u] * ALPHA;
#pragma unroll
        for (int r = 0; r < 4; ++r) fac[r] += ua * lora_up[u * 4 + r];
    }

    float4 t1[4];
#pragma unroll
    for (int r = 0; r < 4; ++r) t1[r] = make_float4(0.f, 0.f, 0.f, 0.f);
    for (int d = 0; d < 100; ++d) {
        float4 da = *(const float4*)(down_aux + d * 1024 + i0);
#pragma unroll
        for (int r = 0; r < 4; ++r) {
            float ld = lora_down[r * 100 + d];
            t1[r].x += ld * da.x; t1[r].y += ld * da.y;
            t1[r].z += ld * da.z; t1[r].w += ld * da.w;
        }
    }

    float4 acc = *(const float4*)(W + (long)o * 1024 + i0);
#pragma unroll
    for (int r = 0; r < 4; ++r) {
        acc.x += fac[r] * t1[r].x; acc.y += fac[r] * t1[r].y;
        acc.z += fac[r] * t1[r].z; acc.w += fac[r] * t1[r].w;
    }

    if (BF16OUT) {
        ushort4 rr;
        rr.x = f32_to_bf16_rne(acc.x); rr.y = f32_to_bf16_rne(acc.y);
        rr.z = f32_to_bf16_rne(acc.z); rr.w = f32_to_bf16_rne(acc.w);
        *(ushort4*)((ushort_t*)weff + (long)o * 1024 + i0) = rr;
    } else {
        *(float4*)((float*)weff + (long)o * 1024 + i0) = acc;
    }
}

// ---------------------------------------------------------------------------
// Fully-fused GEMM: C = cvt_bf16(A_f32[M][K]) * Bt_bf16[N][K]^T + bias
// 256x256x64 tile, 8 waves (2Mx4N), per-wave 128x64 = acc[8][4] f32x4 (AGPR).
// 2-barrier/K-tile counted-sync schedule (R7 structure) with A conversion
// fused into the staging path:
//   A: f32 global -> 16 regs (half-tile) -> cvt_pk -> swizzled ds_write_b128.
//      Two halves per iter: h0 loads pre-Q0 / cvt post-Q0 (cover=Q0);
//      h1 loads post-Q0 / cvt post-Q2 (cover=Q1+Q2). Peak +16 VGPR.
//   B: glds bf16, pre-swizzled global source (L2-resident weff).
//   aH fragment reads issued after Q1 (shrinks fragment live range 96->64).
// Gate per iter: s_waitcnt vmcnt(4) lgkmcnt(0); s_barrier  (only B(j+2) glds
// remain in flight; lgkm drains this iter's A ds_writes).
#define BMM 256
#define BNN 256
#define BKK 64

__global__ __launch_bounds__(512, 2)
void gemm_fused_kernel(const float* __restrict__ A,
                       const ushort_t* __restrict__ Bt,
                       const float* __restrict__ bias,
                       float* __restrict__ C, int M, int N, int K) {
    __shared__ __align__(16) ushort_t Ab[2][BMM * BKK];  // 2 x 32 KB
    __shared__ __align__(16) ushort_t Bb[2][BNN * BKK];  // 2 x 32 KB

    int nTilesN = N / BNN;  // 4
    int nwg = gridDim.x;
    int bid = blockIdx.x;
    int swz = bid;
    if ((nwg & 7) == 0) {   // grid = 1024 -> bijective XCD swizzle
        int cpx = nwg >> 3;
        swz = (bid & 7) * cpx + (bid >> 3);
    }
    int tm = swz / nTilesN;   // 4 blocks sharing an A panel: same (bid&7) ->
    int tn = swz % nTilesN;   // same XCD, back-to-back -> A f32 L2-hot
    const long rowA0 = (long)tm * BMM;
    const long colB0 = (long)tn * BNN;

    int tid = threadIdx.x;
    int lane = tid & 63;
    int wave = tid >> 6;     // 0..7
    int wr = wave >> 2;      // 0..1  (M)
    int wc = wave & 3;       // 0..3  (N)

    // ---- A staging map (per half-tile: 128 rows x 64 k f32 = 32 KB) ----
    // chunk p = q*512 + tid (q=0..1): row-in-half = p>>3 (0..127),
    // 32B-f32 chunk col = p&7 ; LDS 16B-bf16 chunk pos = col ^ (row&7).
    int amrow[2], amcol[2], amlds[2];
#pragma unroll
    for (int q = 0; q < 2; ++q) {
        int p = q * 512 + tid;
        amrow[q] = p >> 3;
        amcol[q] = p & 7;
        amlds[q] = amcol[q] ^ (amrow[q] & 7);
    }

    // ---- B staging map (glds, pre-swizzled source) ----
    int prow[2], pcg[2];
#pragma unroll
    for (int q = 0; q < 2; ++q) {
        int pc = q * 512 + tid;
        prow[q] = pc >> 3;
        pcg[q] = (pc & 7) ^ (prow[q] & 7);
    }

    // fragment map
    int fr = lane & 15;
    int h4 = lane >> 4;
    int s7 = fr & 7;
    int aoff = (wr * 128 + fr) * 64;
    int boff = (wc * 64 + fr) * 64;
    int ck[2] = { (h4 ^ s7) * 8, ((4 + h4) ^ s7) * 8 };

    f32x4 acc[8][4];
#pragma unroll
    for (int m = 0; m < 8; ++m)
#pragma unroll
        for (int n = 0; n < 4; ++n) acc[m][n] = (f32x4)(0.0f);

    const int nIter = K / BKK;  // 16

    float4 vA0[2], vA1[2];   // in-flight A half-tile (16 VGPR)

    auto loadAhalf = [&](int kt, int h) {
        const float* src = A + (rowA0 + h * 128) * (long)K + kt * BKK;
#pragma unroll
        for (int q = 0; q < 2; ++q) {
            const float* gp = src + (long)amrow[q] * K + amcol[q] * 8;
            vA0[q] = ((const float4*)gp)[0];
            vA1[q] = ((const float4*)gp)[1];
        }
    };
    auto writeAhalf = [&](int h, int bufsel) {
        ushort_t* dst = &Ab[bufsel][h * 8192];
#pragma unroll
        for (int q = 0; q < 2; ++q) {
            uint4 w;
            w.x = cvt_pk_bf16(vA0[q].x, vA0[q].y);
            w.y = cvt_pk_bf16(vA0[q].z, vA0[q].w);
            w.z = cvt_pk_bf16(vA1[q].x, vA1[q].y);
            w.w = cvt_pk_bf16(vA1[q].z, vA1[q].w);
            *(uint4*)(dst + amrow[q] * 64 + amlds[q] * 8) = w;
        }
    };
    auto stageB = [&](int kt, int h, int bufsel) {
        const ushort_t* src = Bt + (colB0 + h * 128) * (long)K + kt * BKK;
        ushort_t* dst = &Bb[bufsel][h * 8192 + wave * 512];
#pragma unroll
        for (int q = 0; q < 2; ++q)
            async_copy16(src + (long)prow[q] * K + pcg[q] * 8, dst + q * 4096);
    };

    // ---------------- prologue ----------------
    stageB(0, 0, 0); stageB(0, 1, 0);     // B(0) -> buf0   (4 glds)
    loadAhalf(0, 0);
    writeAhalf(0, 0);                     // waits A(0)h0 (~HBM latency, once)
    loadAhalf(0, 1);
    writeAhalf(1, 0);                     // A(0) -> buf0 complete
    stageB(1, 0, 1); stageB(1, 1, 1);     // B(1) -> buf1   (4 glds)
    asm volatile("s_waitcnt vmcnt(4) lgkmcnt(0)" ::: "memory");  // B(0) landed
    __builtin_amdgcn_s_barrier();

#pragma unroll 1
    for (int j = 0; j < nIter; ++j) {
        int c = j & 1, o = c ^ 1;
        const ushort_t* Ac = &Ab[c][0];
        const ushort_t* Bc = &Bb[c][0];
        bool stage1 = (j + 1 < nIter);
        bool stage2 = (j + 2 < nIter);

        // ---- fragment reads: aL, bL, bH  (aH deferred past Q1) ----
        bf16x8 aL[4][2], aH[4][2], bL[2][2], bH[2][2];
#pragma unroll
        for (int m = 0; m < 4; ++m)
#pragma unroll
            for (int kk = 0; kk < 2; ++kk)
                aL[m][kk] = *(const bf16x8*)&Ac[aoff + m * 1024 + ck[kk]];
#pragma unroll
        for (int n = 0; n < 2; ++n)
#pragma unroll
            for (int kk = 0; kk < 2; ++kk)
                bL[n][kk] = *(const bf16x8*)&Bc[boff + n * 1024 + ck[kk]];
#pragma unroll
        for (int n = 0; n < 2; ++n)
#pragma unroll
            for (int kk = 0; kk < 2; ++kk)
                bH[n][kk] = *(const bf16x8*)&Bc[boff + (n + 2) * 1024 + ck[kk]];

        // issue A(j+1) half0 f32 loads (consumed after Q0)
        if (stage1) loadAhalf(j + 1, 0);

        // ---- Q0: aL x bL ----
        __builtin_amdgcn_s_setprio(1);
#pragma unroll
        for (int m = 0; m < 4; ++m)
#pragma unroll
            for (int n = 0; n < 2; ++n)
#pragma unroll
                for (int kk = 0; kk < 2; ++kk)
                    acc[m][n] = __builtin_amdgcn_mfma_f32_16x16x32_bf16(
                        aL[m][kk], bL[n][kk], acc[m][n], 0, 0, 0);
        __builtin_amdgcn_s_setprio(0);

        // cvt+write A(j+1)h0 -> buf o ; issue A(j+1)h1 loads
        if (stage1) {
            writeAhalf(0, o);
            loadAhalf(j + 1, 1);
        }

        // ---- Q1: aL x bH ----
        __builtin_amdgcn_s_setprio(1);
#pragma unroll
        for (int m = 0; m < 4; ++m)
#pragma unroll
            for (int n = 0; n < 2; ++n)
#pragma unroll
                for (int kk = 0; kk < 2; ++kk)
                    acc[m][n + 2] = __builtin_amdgcn_mfma_f32_16x16x32_bf16(
                        aL[m][kk], bH[n][kk], acc[m][n + 2], 0, 0, 0);
        __builtin_amdgcn_s_setprio(0);

        // deferred aH fragment reads (stream under Q2's counted lgkm)
#pragma unroll
        for (int m = 0; m < 4; ++m)
#pragma unroll
            for (int kk = 0; kk < 2; ++kk)
                aH[m][kk] = *(const bf16x8*)&Ac[aoff + (m + 4) * 1024 + ck[kk]];

        // ---- Q2: aH x bH ----
        __builtin_amdgcn_s_setprio(1);
#pragma unroll
        for (int m = 0; m < 4; ++m)
#pragma unroll
            for (int n = 0; n < 2; ++n)
#pragma unroll
                for (int kk = 0; kk < 2; ++kk)
                    acc[m + 4][n + 2] = __builtin_amdgcn_mfma_f32_16x16x32_bf16(
                        aH[m][kk], bH[n][kk], acc[m + 4][n + 2], 0, 0, 0);
        __builtin_amdgcn_s_setprio(0);

        // cvt+write A(j+1)h1 -> buf o (reads of buf o retired at iter j-1 Q2)
        if (stage1) writeAhalf(1, o);

        // all waves' reads of buf c retired (Q2 consumed the last ones)
        __builtin_amdgcn_s_barrier();            // B2

        if (stage2) { stageB(j + 2, 0, c); stageB(j + 2, 1, c); }

        // ---- Q3: aH x bL (pure-reg; overlaps glds flight) ----
        __builtin_amdgcn_s_setprio(1);
#pragma unroll
        for (int m = 0; m < 4; ++m)
#pragma unroll
            for (int n = 0; n < 2; ++n)
#pragma unroll
                for (int kk = 0; kk < 2; ++kk)
                    acc[m + 4][n] = __builtin_amdgcn_mfma_f32_16x16x32_bf16(
                        aH[m][kk], bL[n][kk], acc[m + 4][n], 0, 0, 0);
        __builtin_amdgcn_s_setprio(0);

        // gate: B(j+1) landed + this iter's A ds_writes visible
        if (stage2) {
            asm volatile("s_waitcnt vmcnt(4) lgkmcnt(0)" ::: "memory");
        } else {
            asm volatile("s_waitcnt vmcnt(0) lgkmcnt(0)" ::: "memory");
        }
        __builtin_amdgcn_s_barrier();            // B0
    }

    // ---- epilogue: C = acc + bias ----
    int ccol = lane & 15;
    int crow = (lane >> 4) * 4;
#pragma unroll
    for (int m = 0; m < 8; ++m) {
        long grow = rowA0 + wr * 128 + m * 16 + crow;
#pragma unroll
        for (int n = 0; n < 4; ++n) {
            long gcol = colB0 + wc * 64 + n * 16 + ccol;
            float bb = bias[gcol];
#pragma unroll
            for (int r = 0; r < 4; ++r) {
                C[(grow + r) * N + gcol] = acc[m][n][r] + bb;
            }
        }
    }
}

// ---------------------------------------------------------------------------
// Fallback: plain f32 tiled GEMM (used only if ws too small for bf16 path)
__global__ __launch_bounds__(256)
void gemm_f32_fallback(const float* __restrict__ A, const float* __restrict__ Bt,
                       const float* __restrict__ bias, float* __restrict__ C,
                       int M, int N, int K) {
    __shared__ float As[64][17];
    __shared__ float Bs[64][17];
    int tilesN = N / 64;
    int tm = blockIdx.x / tilesN;
    int tn = blockIdx.x % tilesN;
    int tid = threadIdx.x;
    int tr = tid / 16, tc = tid % 16;
    float acc[4][4] = {};
    for (int k0 = 0; k0 < K; k0 += 16) {
        for (int t = tid; t < 64 * 16; t += 256) {
            int r = t / 16, c = t % 16;
            As[r][c] = A[((long)tm * 64 + r) * K + k0 + c];
            Bs[r][c] = Bt[((long)tn * 64 + r) * K + k0 + c];
        }
        __syncthreads();
#pragma unroll
        for (int kk = 0; kk < 16; ++kk) {
            float av[4], bv[4];
#pragma unroll
            for (int i = 0; i < 4; ++i) av[i] = As[tr * 4 + i][kk];
#pragma unroll
            for (int j = 0; j < 4; ++j) bv[j] = Bs[tc * 4 + j][kk];
#pragma unroll
            for (int i = 0; i < 4; ++i)
#pragma unroll
                for (int j = 0; j < 4; ++j) acc[i][j] += av[i] * bv[j];
        }
        __syncthreads();
    }
#pragma unroll
    for (int i = 0; i < 4; ++i) {
        long row = (long)tm * 64 + tr * 4 + i;
#pragma unroll
        for (int j = 0; j < 4; ++j) {
            long col = (long)tn * 64 + tc * 4 + j;
            C[row * N + col] = acc[i][j] + bias[col];
        }
    }
}

// ---------------------------------------------------------------------------
extern "C" void kernel_launch(void* const* d_in, const int* in_sizes, int n_in,
                              void* d_out, int out_size, void* d_ws, size_t ws_size,
                              hipStream_t stream) {
    const float* hs        = (const float*)d_in[0];
    const float* W         = (const float*)d_in[1];
    const float* b         = (const float*)d_in[2];
    const float* lora_down = (const float*)d_in[3];
    const float* lora_up   = (const float*)d_in[4];
    const float* down_aux  = (const float*)d_in[5];
    const float* up_aux    = (const float*)d_in[6];
    float* out = (float*)d_out;

    const int K = 1024;   // IN
    const int N = 1024;   // OUT
    const int M = in_sizes[0] / K;  // B*S = 65536

    char* ws = (char*)d_ws;
    const size_t NEED_FAST = 2 * 1024 * 1024;   // weff bf16 only

    if (ws_size >= NEED_FAST && (M % BMM) == 0) {
        ushort_t* weff = (ushort_t*)ws;
        weff_fused_kernel<true><<<N, 256, 0, stream>>>(W, lora_down, lora_up,
                                                       down_aux, up_aux, weff);
        int grid = (M / BMM) * (N / BNN);   // 1024
        gemm_fused_kernel<<<grid, 512, 0, stream>>>(hs, weff, b, out, M, N, K);
    } else {
        float* weff = (float*)ws;  // 4MB
        weff_fused_kernel<false><<<N, 256, 0, stream>>>(W, lora_down, lora_up,
                                                        down_aux, up_aux, weff);
        int grid = (M / 64) * (N / 64);
        gemm_f32_fallback<<<grid, 256, 0, stream>>>(hs, weff, b, out, M, N, K);
    }
}